// Round 2
// baseline (17232.935 us; speedup 1.0000x reference)
//
#include <hip/hip_runtime.h>
#include <cstddef>

typedef unsigned short u16;
typedef unsigned int u32;

// ---------------- constants ----------------
#define S_LEN   2048
#define H_TOT   4096
#define NHIST   1024
#define D_LOC   512
#define D_TIM   64
#define D_UID   64
#define HID     512
#define D_IN    576      // D_LOC + D_TIM
#define TARGET  1024
#define NLOC    50000
#define D_OUT   1088     // 2*HID + D_UID
#define G3      1536     // 3*HID

// ---------------- helpers ----------------
__device__ __forceinline__ u16 f2bf(float f) {
    u32 x; __builtin_memcpy(&x, &f, 4);
    u32 r = x + 0x7fffu + ((x >> 16) & 1u);
    return (u16)(r >> 16);
}
__device__ __forceinline__ float bf2f(u16 u) {
    u32 x = ((u32)u) << 16;
    float f; __builtin_memcpy(&f, &x, 4); return f;
}
__device__ __forceinline__ float u32_as_f32(u32 x) {
    float f; __builtin_memcpy(&f, &x, 4); return f;
}
__device__ __forceinline__ float sigm(float x) {
    return 1.0f / (1.0f + __expf(-x));
}
__device__ __forceinline__ float tanh_stable(float x) {
    float a = __expf(-2.0f * fabsf(x));
    float t = (1.0f - a) / (1.0f + a);
    return copysignf(t, x);
}
__device__ __forceinline__ u32 pk(float a, float b) {
    return (u32)f2bf(a) | ((u32)f2bf(b) << 16);
}
// L1-bypassing load: served by the XCD-shared L2 (coherence point within one XCD)
__device__ __forceinline__ u32 ld_sc0(const u32* p) {
    u32 v;
    asm volatile("global_load_dword %0, %1, off sc0\n\ts_waitcnt vmcnt(0)"
                 : "=v"(v) : "v"(p));
    return v;
}
// L2-resident store: write-through L1 into the XCD-shared L2 (does NOT go to MALL)
__device__ __forceinline__ void st_sc0(u32* p, u32 v) {
    asm volatile("global_store_dword %0, %1, off sc0" :: "v"(p), "v"(v) : "memory");
}

typedef __bf16 bf16x8 __attribute__((ext_vector_type(8)));
typedef float  f32x4  __attribute__((ext_vector_type(4)));

// ---------------- K0: exclusive scan of counts (+ zero GRU team-ctrl words) ----------------
__global__ __launch_bounds__(1024) void scan_kernel(const int* __restrict__ counts,
                                                    int* __restrict__ offs,
                                                    u32* __restrict__ ctrl) {
    __shared__ int s[NHIST];
    int tid = threadIdx.x;
    if (tid < 16) ctrl[tid] = 0;   // per-XCD registration counters + chosen flag
    int v = counts[tid];
    s[tid] = v;
    __syncthreads();
    for (int d = 1; d < NHIST; d <<= 1) {
        int t = (tid >= d) ? s[tid - d] : 0;
        __syncthreads();
        s[tid] += t;
        __syncthreads();
    }
    offs[tid] = s[tid] - v;
}

// ---------------- K1: hist2 = [segment_mean(emb_loc), emb_tim at offset] (bf16 out) ----------------
__global__ __launch_bounds__(64) void hist_kernel(const int* __restrict__ hloc,
                                                  const int* __restrict__ htim,
                                                  const int* __restrict__ counts,
                                                  const int* __restrict__ offs,
                                                  const float* __restrict__ emb_loc,
                                                  const float* __restrict__ emb_tim,
                                                  u16* __restrict__ hist2) {
    int i = blockIdx.x, c = threadIdx.x;   // c in [0,64)
    int off = offs[i], cnt = counts[i];
    float a[8] = {};
    for (int k = 0; k < cnt; k++) {
        int kk = off + k; if (kk >= H_TOT) break;
        const float* p = emb_loc + (size_t)hloc[kk] * D_LOC + c * 8;
        float4 q0 = ((const float4*)p)[0];
        float4 q1 = ((const float4*)p)[1];
        a[0] += q0.x; a[1] += q0.y; a[2] += q0.z; a[3] += q0.w;
        a[4] += q1.x; a[5] += q1.y; a[6] += q1.z; a[7] += q1.w;
    }
    float inv = (cnt > 0) ? 1.0f / (float)cnt : 0.0f;
    u16* o = hist2 + (size_t)i * D_IN + c * 8;
    #pragma unroll
    for (int j = 0; j < 8; j++) o[j] = f2bf(a[j] * inv);
    // tim part: row at segment start
    hist2[(size_t)i * D_IN + D_LOC + c] = f2bf(emb_tim[(size_t)htim[off] * D_TIM + c]);
}

// ---------------- K2: x = [emb_loc[loc], emb_tim[tim]] (bf16 out) ----------------
__global__ __launch_bounds__(256) void build_x_kernel(const int* __restrict__ loc,
                                                      const int* __restrict__ tim,
                                                      const float* __restrict__ emb_loc,
                                                      const float* __restrict__ emb_tim,
                                                      u16* __restrict__ x) {
    int idx = blockIdx.x * 256 + threadIdx.x;    // < S_LEN * D_IN
    int row = idx / D_IN, col = idx - row * D_IN;
    float v = (col < D_LOC) ? emb_loc[(size_t)loc[row] * D_LOC + col]
                            : emb_tim[(size_t)tim[row] * D_TIM + (col - D_LOC)];
    x[idx] = f2bf(v);
}

// ---------------- K2b: uid columns of outbuf ----------------
__global__ __launch_bounds__(256) void uid_kernel(const int* __restrict__ uid,
                                                  const float* __restrict__ emb_uid,
                                                  u16* __restrict__ outbuf) {
    int idx = blockIdx.x * 256 + threadIdx.x;    // < TARGET * D_UID
    int row = idx >> 6, c = idx & 63;
    outbuf[(size_t)row * D_OUT + 2 * HID + c] = f2bf(emb_uid[(size_t)uid[0] * D_UID + c]);
}

// ---------------- GEMM: C(MxN) = A(MxK) @ B(NxK)^T [+bias][tanh][transposed copy] ----------------
// EPI bits: 1=bias, 2=tanh, 4=transposed bf16 store to Ct (ldt)
// AF32/BF32: source dtype of A/B (fp32 converts to bf16 at staging)
template<int EPI, bool OBF16, bool NG, bool AF32, bool BF32>
__global__ __launch_bounds__(256)
void gemm_bt_kernel(const void* __restrict__ Ap, const void* __restrict__ Bp,
                    void* __restrict__ Cp, const float* __restrict__ bias,
                    u16* __restrict__ Ct,
                    int M, int N, int K, int lda, int ldb, int ldc, int ldt) {
    __shared__ __align__(16) u16 sA[128 * 64];
    __shared__ __align__(16) u16 sB[128 * 64];
    const int tid = threadIdx.x;
    const int w = tid >> 6, lane = tid & 63;
    const int wr = (w >> 1) * 64, wc = (w & 1) * 64;
    const int m0 = blockIdx.y * 128, n0 = blockIdx.x * 128;
    f32x4 acc[4][4] = {};
    const int srow = w * 32 + (lane >> 3);   // + i*8
    const int scol = (lane & 7) * 8;         // element col within tile K=64

    for (int kt = 0; kt < K; kt += 64) {
        #pragma unroll
        for (int i = 0; i < 4; i++) {
            int rt = srow + i * 8;
            int ra = m0 + rt;
            if (AF32) {
                const float* s = (const float*)Ap + (size_t)ra * lda + kt + scol;
                float4 x0 = ((const float4*)s)[0];
                float4 x1 = ((const float4*)s)[1];
                uint4 q = { pk(x0.x, x0.y), pk(x0.z, x0.w), pk(x1.x, x1.y), pk(x1.z, x1.w) };
                *(uint4*)&sA[rt * 64 + scol] = q;
            } else {
                *(uint4*)&sA[rt * 64 + scol] =
                    *(const uint4*)((const u16*)Ap + (size_t)ra * lda + kt + scol);
            }
            int rb = n0 + rt;
            if (NG) rb = (rb < N - 1) ? rb : (N - 1);
            if (BF32) {
                const float* s = (const float*)Bp + (size_t)rb * ldb + kt + scol;
                float4 x0 = ((const float4*)s)[0];
                float4 x1 = ((const float4*)s)[1];
                uint4 q = { pk(x0.x, x0.y), pk(x0.z, x0.w), pk(x1.x, x1.y), pk(x1.z, x1.w) };
                *(uint4*)&sB[rt * 64 + scol] = q;
            } else {
                *(uint4*)&sB[rt * 64 + scol] =
                    *(const uint4*)((const u16*)Bp + (size_t)rb * ldb + kt + scol);
            }
        }
        __syncthreads();
        #pragma unroll
        for (int kk = 0; kk < 64; kk += 32) {
            const int krow = kk + (lane >> 4) * 8;
            bf16x8 af[4], bf_[4];
            #pragma unroll
            for (int mi = 0; mi < 4; mi++)
                af[mi] = *(const bf16x8*)&sA[(wr + mi * 16 + (lane & 15)) * 64 + krow];
            #pragma unroll
            for (int ni = 0; ni < 4; ni++)
                bf_[ni] = *(const bf16x8*)&sB[(wc + ni * 16 + (lane & 15)) * 64 + krow];
            #pragma unroll
            for (int mi = 0; mi < 4; mi++)
                #pragma unroll
                for (int ni = 0; ni < 4; ni++)
                    acc[mi][ni] = __builtin_amdgcn_mfma_f32_16x16x32_bf16(
                        af[mi], bf_[ni], acc[mi][ni], 0, 0, 0);
        }
        __syncthreads();
    }
    // epilogue: D col = lane&15, row = (lane>>4)*4 + reg
    #pragma unroll
    for (int mi = 0; mi < 4; mi++) {
        #pragma unroll
        for (int ni = 0; ni < 4; ni++) {
            int gc = n0 + wc + ni * 16 + (lane & 15);
            if (NG && gc >= N) continue;
            #pragma unroll
            for (int r = 0; r < 4; r++) {
                int gr = m0 + wr + mi * 16 + (lane >> 4) * 4 + r;
                float v = acc[mi][ni][r];
                if (EPI & 1) v += bias[gc];
                if (EPI & 2) v = tanh_stable(v);
                if (OBF16) ((u16*)Cp)[(size_t)gr * ldc + gc] = f2bf(v);
                else       ((float*)Cp)[(size_t)gr * ldc + gc] = v;
                if (EPI & 4) Ct[(size_t)gc * ldt + gr] = f2bf(v);
            }
        }
    }
}

// ---------------- GRU: 16 co-resident blocks ON ONE XCD, tag-packed h exchange ----------------
// block (team rank) b owns h[32b..32b+32); holds w_hh rows {g*512 + 32b + jj} in VGPRs (fp32).
// thread layout: tid = qd*96 + wr, wr = g*32+jj, qd = quarter of K (128 each).
// Exchange protocol (round-2 fix): producer stores each packed word TWICE —
//   (a) sc0-only store into hcomm  -> write-through L1 into the XCD-SHARED L2 (fast path)
//   (b) agent-scope store into hcomm2 -> MALL (slow safety path)
// Consumers spin on hcomm with sc0 loads (L2-served, ~200cy round trip); every 32nd
// iteration they check hcomm2 at agent scope so the loop terminates even if the
// same-XCD-L2 coherence assumption is wrong (degrades to ~baseline speed, no hang).
#define GRU_BLOCKS 16
#define GRU_GRID   128
__global__ __launch_bounds__(384, 2)
void gru_kernel(const float* __restrict__ gi, const float* __restrict__ w_hh,
                const float* __restrict__ b_hh, u32* __restrict__ hcomm,
                u32* __restrict__ hcomm2,
                u16* __restrict__ outbuf, u32* __restrict__ ctrl) {
    // ---- team registration (ctrl[0..7]=per-XCD count, ctrl[8]=chosen XCD+1) ----
    __shared__ int s_b;
    if (threadIdx.x == 0) {
        u32 xcc;
        asm volatile("s_getreg_b32 %0, hwreg(HW_REG_XCC_ID)" : "=s"(xcc));
        xcc &= 7u;
        u32 r = __hip_atomic_fetch_add(&ctrl[xcc], 1u,
                                       __ATOMIC_RELAXED, __HIP_MEMORY_SCOPE_AGENT);
        if (r == GRU_BLOCKS - 1) {
            u32 expected = 0u;
            __hip_atomic_compare_exchange_strong(&ctrl[8], &expected, xcc + 1u,
                __ATOMIC_RELAXED, __ATOMIC_RELAXED, __HIP_MEMORY_SCOPE_AGENT);
        }
        u32 ch;
        do {
            ch = __hip_atomic_load(&ctrl[8], __ATOMIC_RELAXED, __HIP_MEMORY_SCOPE_AGENT);
        } while (ch == 0u);
        s_b = (r < GRU_BLOCKS && ch == xcc + 1u) ? (int)r : -1;
    }
    __syncthreads();
    const int b = s_b;
    if (b < 0) return;

    const int tid = threadIdx.x;
    const int wr = tid % 96, qd = tid / 96;
    const int g = wr >> 5, jj = wr & 31;
    const int grow = g * HID + b * 32 + jj;     // row of w_hh / gi

    __shared__ __align__(16) float hbuf[HID];
    __shared__ float psum[96 * 4];
    __shared__ float ghh[96], gii[96];

    // preload weights: 128 fp32 in regs
    float wreg[128];
    {
        const float4* wp = (const float4*)(w_hh + (size_t)grow * HID + qd * 128);
        #pragma unroll
        for (int c = 0; c < 32; c++) {
            float4 v = wp[c];
            wreg[c * 4 + 0] = v.x; wreg[c * 4 + 1] = v.y;
            wreg[c * 4 + 2] = v.z; wreg[c * 4 + 3] = v.w;
        }
    }
    float bhh = b_hh[grow];
    for (int i = tid; i < HID; i += 384) hbuf[i] = 0.0f;
    float gi_cur = (qd == 0) ? gi[grow] : 0.0f;
    __syncthreads();

    for (int t = 0; t < S_LEN; t++) {
        // Phase 1: partial dot (reads full hbuf; LDS reads broadcast within wave)
        float acc = 0.0f;
        const float4* hp = (const float4*)(hbuf + qd * 128);
        #pragma unroll
        for (int c = 0; c < 32; c++) {
            float4 h4 = hp[c];
            acc = fmaf(wreg[4 * c + 0], h4.x, acc);
            acc = fmaf(wreg[4 * c + 1], h4.y, acc);
            acc = fmaf(wreg[4 * c + 2], h4.z, acc);
            acc = fmaf(wreg[4 * c + 3], h4.w, acc);
        }
        psum[wr * 4 + qd] = acc;
        __syncthreads();                                   // S1
        if (tid < 96) {
            float s = psum[tid * 4] + psum[tid * 4 + 1] + psum[tid * 4 + 2] + psum[tid * 4 + 3];
            ghh[tid] = s + bhh;
            gii[tid] = gi_cur;
        }
        __syncthreads();                                   // S2

        const u32 want = (u32)(t + 1);
        const int p = (t + 1) & 1;
        if (tid < 32) {
            float r = sigm(gii[tid] + ghh[tid]);
            float z = sigm(gii[32 + tid] + ghh[32 + tid]);
            float n = tanh_stable(gii[64 + tid] + r * ghh[64 + tid]);
            float hn = (1.0f - z) * n + z * hbuf[b * 32 + tid];
            u32 bits = (u32)f2bf(hn);
            u32 word = (bits << 16) | want;
            st_sc0(&hcomm[p * HID + b * 32 + tid], word);          // fast: XCD L2
            __hip_atomic_store(&hcomm2[p * HID + b * 32 + tid], word,
                               __ATOMIC_RELAXED, __HIP_MEMORY_SCOPE_AGENT); // safety: MALL
            if (t >= (S_LEN - TARGET))
                outbuf[(size_t)(t - (S_LEN - TARGET)) * D_OUT + b * 32 + tid] = (u16)bits;
        }
        // prefetch next gi row element
        float gi_nxt = 0.0f;
        if (qd == 0) {
            int tn = (t + 1 < S_LEN) ? (t + 1) : (S_LEN - 1);
            gi_nxt = gi[(size_t)tn * G3 + grow];
        }
        // poll all 512 packed words for tag t+1 (skip after last step)
        if (t < S_LEN - 1) {
            const int w0 = tid;
            const int w1 = (tid < 128) ? (384 + tid) : -1;
            bool d0 = false, d1 = (w1 < 0);
            int spin = 0;
            while (!d0 || !d1) {
                ++spin;
                bool fb = (spin & 31) == 0;
                if (!d0) {
                    u32 v = fb ? __hip_atomic_load(&hcomm2[p * HID + w0], __ATOMIC_RELAXED,
                                                   __HIP_MEMORY_SCOPE_AGENT)
                               : ld_sc0(&hcomm[p * HID + w0]);
                    if ((v & 0xffffu) == want) { hbuf[w0] = u32_as_f32(v & 0xffff0000u); d0 = true; }
                }
                if (!d1) {
                    u32 v = fb ? __hip_atomic_load(&hcomm2[p * HID + w1], __ATOMIC_RELAXED,
                                                   __HIP_MEMORY_SCOPE_AGENT)
                               : ld_sc0(&hcomm[p * HID + w1]);
                    if ((v & 0xffffu) == want) { hbuf[w1] = u32_as_f32(v & 0xffff0000u); d1 = true; }
                }
            }
        }
        __syncthreads();                                   // S3
        gi_cur = gi_nxt;
    }
}

// ---------------- softmax over 1024 cols (scores fp32 -> attn bf16) ----------------
__global__ __launch_bounds__(256) void softmax_kernel(const float* __restrict__ sc,
                                                      u16* __restrict__ attn) {
    int r = blockIdx.x, tid = threadIdx.x;
    int lane = tid & 63, wv = tid >> 6;
    const float* row = sc + (size_t)r * NHIST;
    float v[4], m = -3.4e38f;
    #pragma unroll
    for (int k = 0; k < 4; k++) { v[k] = row[tid + 256 * k]; m = fmaxf(m, v[k]); }
    #pragma unroll
    for (int o = 32; o >= 1; o >>= 1) m = fmaxf(m, __shfl_xor(m, o));
    __shared__ float rmax[4], rsum[4];
    if (lane == 0) rmax[wv] = m;
    __syncthreads();
    m = fmaxf(fmaxf(rmax[0], rmax[1]), fmaxf(rmax[2], rmax[3]));
    float s = 0.0f;
    #pragma unroll
    for (int k = 0; k < 4; k++) { v[k] = __expf(v[k] - m); s += v[k]; }
    #pragma unroll
    for (int o = 32; o >= 1; o >>= 1) s += __shfl_xor(s, o);
    if (lane == 0) rsum[wv] = s;
    __syncthreads();
    s = rsum[0] + rsum[1] + rsum[2] + rsum[3];
    float inv = 1.0f / s;
    #pragma unroll
    for (int k = 0; k < 4; k++) attn[(size_t)r * NHIST + tid + 256 * k] = f2bf(v[k] * inv);
}

// ---------------- log_softmax in place over d_out rows (fp32) ----------------
__global__ __launch_bounds__(1024) void logsoftmax_kernel(float* __restrict__ y) {
    int r = blockIdx.x, tid = threadIdx.x;
    int lane = tid & 63, wv = tid >> 6;
    float* row = y + (size_t)r * NLOC;
    __shared__ float red[16];
    float m = -3.4e38f;
    for (int i = tid; i < NLOC; i += 1024) m = fmaxf(m, row[i]);
    #pragma unroll
    for (int o = 32; o >= 1; o >>= 1) m = fmaxf(m, __shfl_xor(m, o));
    if (lane == 0) red[wv] = m;
    __syncthreads();
    #pragma unroll
    for (int k = 0; k < 16; k++) m = fmaxf(m, red[k]);
    __syncthreads();
    float s = 0.0f;
    for (int i = tid; i < NLOC; i += 1024) s += __expf(row[i] - m);
    #pragma unroll
    for (int o = 32; o >= 1; o >>= 1) s += __shfl_xor(s, o);
    if (lane == 0) red[wv] = s;
    __syncthreads();
    float tot = 0.0f;
    #pragma unroll
    for (int k = 0; k < 16; k++) tot += red[k];
    float lse = m + logf(tot);
    for (int i = tid; i < NLOC; i += 1024) row[i] = row[i] - lse;
}

// ---------------- launch ----------------
extern "C" void kernel_launch(void* const* d_in, const int* in_sizes, int n_in,
                              void* d_out, int out_size, void* d_ws, size_t ws_size,
                              hipStream_t stream) {
    const int*   loc       = (const int*)d_in[0];
    const int*   tim       = (const int*)d_in[1];
    const int*   hloc      = (const int*)d_in[2];
    const int*   htim      = (const int*)d_in[3];
    const int*   counts    = (const int*)d_in[4];
    const int*   uid       = (const int*)d_in[5];
    // d_in[6] = target_len (1024, constant)
    const float* emb_loc   = (const float*)d_in[7];
    const float* emb_tim   = (const float*)d_in[8];
    const float* emb_uid   = (const float*)d_in[9];
    const float* fc_attn_w = (const float*)d_in[10];
    const float* fc_attn_b = (const float*)d_in[11];
    const float* w_ih      = (const float*)d_in[12];
    const float* w_hh      = (const float*)d_in[13];
    const float* b_ih      = (const float*)d_in[14];
    const float* b_hh      = (const float*)d_in[15];
    const float* fc_final_w= (const float*)d_in[16];
    const float* fc_final_b= (const float*)d_in[17];

    char* ws = (char*)d_ws;
    int*   offs     = (int*)(ws + 0);                  //   4 KB
    u32*   hcomm    = (u32*)(ws + 4096);               //   4 KB (L2 fast path)
    u16*   hist2    = (u16*)(ws + 8192);               // 1024*576*2
    u16*   xbuf     = (u16*)(ws + 1187840);            // 2048*576*2
    u16*   history  = (u16*)(ws + 3547136);            // 1024*512*2
    u16*   historyT = (u16*)(ws + 4595712);            // 512*1024*2
    u16*   outbuf   = (u16*)(ws + 5644288);            // 1024*1088*2
    float* scores   = (float*)(ws + 7872512);          // 1024*1024*4
    u16*   attn     = (u16*)(ws + 12066816);           // 1024*1024*2
    float* gi       = (float*)(ws + 14163968);         // 2048*1536*4 -> end 26746880
    // GRU team-ctrl + MALL-path mirror overlap the attn region (attn written only
    // AFTER gru); ctrl zeroed by scan_kernel each launch (graph-replay safe);
    // hcomm2 needs no zeroing (tag discipline: stale final tag 2047/2048 != want 1).
    u32*   ctrl     = (u32*)(ws + 12066816);
    u32*   hcomm2   = (u32*)(ws + 12066816 + 256);     // 4 KB (agent/MALL safety path)

    float* out = (float*)d_out;

    // prep
    scan_kernel<<<1, 1024, 0, stream>>>(counts, offs, ctrl);
    hist_kernel<<<NHIST, 64, 0, stream>>>(hloc, htim, counts, offs, emb_loc, emb_tim, hist2);
    build_x_kernel<<<(S_LEN * D_IN) / 256, 256, 0, stream>>>(loc, tim, emb_loc, emb_tim, xbuf);
    uid_kernel<<<(TARGET * D_UID) / 256, 256, 0, stream>>>(uid, emb_uid, outbuf);

    // history = tanh(hist2 @ fc_attn_w^T + b) (bf16), plus transposed copy
    gemm_bt_kernel<1 | 2 | 4, true, false, false, true><<<dim3(HID / 128, NHIST / 128), 256, 0, stream>>>(
        hist2, fc_attn_w, history, fc_attn_b, historyT,
        NHIST, HID, D_IN, D_IN, D_IN, HID, NHIST);

    // gi = x @ w_ih^T + b_ih (fp32 out)
    gemm_bt_kernel<1, false, false, false, true><<<dim3(G3 / 128, S_LEN / 128), 256, 0, stream>>>(
        xbuf, w_ih, gi, b_ih, nullptr,
        S_LEN, G3, D_IN, D_IN, D_IN, G3, 0);

    // sequential GRU (writes q -> outbuf cols [0,512)); team of 16 blocks on one XCD
    gru_kernel<<<GRU_GRID, 384, 0, stream>>>(gi, w_hh, b_hh, hcomm, hcomm2, outbuf, ctrl);

    // scores = q @ history^T (fp32)
    gemm_bt_kernel<0, false, false, false, false><<<dim3(NHIST / 128, TARGET / 128), 256, 0, stream>>>(
        outbuf, history, scores, nullptr, nullptr,
        TARGET, NHIST, HID, D_OUT, HID, NHIST, 0);

    // attn = softmax(scores)  (bf16)
    softmax_kernel<<<TARGET, 256, 0, stream>>>(scores, attn);

    // context = attn @ history -> outbuf cols [512,1024)
    gemm_bt_kernel<0, true, false, false, false><<<dim3(HID / 128, TARGET / 128), 256, 0, stream>>>(
        attn, historyT, outbuf + HID, nullptr, nullptr,
        TARGET, HID, NHIST, NHIST, NHIST, D_OUT, 0);

    // y = outbuf @ fc_final_w^T + b -> d_out (fp32), N ragged
    gemm_bt_kernel<1, false, true, false, true><<<dim3((NLOC + 127) / 128, TARGET / 128), 256, 0, stream>>>(
        outbuf, fc_final_w, out, fc_final_b, nullptr,
        TARGET, NLOC, D_OUT, D_OUT, D_OUT, NLOC, 0);

    // log_softmax in place
    logsoftmax_kernel<<<TARGET, 1024, 0, stream>>>(out);
}

// Round 4
// 4355.629 us; speedup vs baseline: 3.9565x; 3.9565x over previous
//
#include <hip/hip_runtime.h>
#include <cstddef>

typedef unsigned short u16;
typedef unsigned int u32;
typedef unsigned long long u64;

// ---------------- constants ----------------
#define S_LEN   2048
#define H_TOT   4096
#define NHIST   1024
#define D_LOC   512
#define D_TIM   64
#define D_UID   64
#define HID     512
#define D_IN    576      // D_LOC + D_TIM
#define TARGET  1024
#define NLOC    50000
#define D_OUT   1088     // 2*HID + D_UID
#define G3      1536     // 3*HID

// ---------------- helpers ----------------
__device__ __forceinline__ u16 f2bf(float f) {
    u32 x; __builtin_memcpy(&x, &f, 4);
    u32 r = x + 0x7fffu + ((x >> 16) & 1u);
    return (u16)(r >> 16);
}
__device__ __forceinline__ float bf2f(u16 u) {
    u32 x = ((u32)u) << 16;
    float f; __builtin_memcpy(&f, &x, 4); return f;
}
__device__ __forceinline__ float u32_as_f32(u32 x) {
    float f; __builtin_memcpy(&f, &x, 4); return f;
}
__device__ __forceinline__ float sigm(float x) {
    return 1.0f / (1.0f + __expf(-x));
}
__device__ __forceinline__ float tanh_stable(float x) {
    float a = __expf(-2.0f * fabsf(x));
    float t = (1.0f - a) / (1.0f + a);
    return copysignf(t, x);
}
__device__ __forceinline__ u32 pk(float a, float b) {
    return (u32)f2bf(a) | ((u32)f2bf(b) << 16);
}

typedef __bf16 bf16x8 __attribute__((ext_vector_type(8)));
typedef float  f32x4  __attribute__((ext_vector_type(4)));

// ---------------- K0: exclusive scan of counts ----------------
__global__ __launch_bounds__(1024) void scan_kernel(const int* __restrict__ counts,
                                                    int* __restrict__ offs) {
    __shared__ int s[NHIST];
    int tid = threadIdx.x;
    int v = counts[tid];
    s[tid] = v;
    __syncthreads();
    for (int d = 1; d < NHIST; d <<= 1) {
        int t = (tid >= d) ? s[tid - d] : 0;
        __syncthreads();
        s[tid] += t;
        __syncthreads();
    }
    offs[tid] = s[tid] - v;
}

// ---------------- K1: hist2 = [segment_mean(emb_loc), emb_tim at offset] (bf16 out) ----------------
__global__ __launch_bounds__(64) void hist_kernel(const int* __restrict__ hloc,
                                                  const int* __restrict__ htim,
                                                  const int* __restrict__ counts,
                                                  const int* __restrict__ offs,
                                                  const float* __restrict__ emb_loc,
                                                  const float* __restrict__ emb_tim,
                                                  u16* __restrict__ hist2) {
    int i = blockIdx.x, c = threadIdx.x;   // c in [0,64)
    int off = offs[i], cnt = counts[i];
    float a[8] = {};
    for (int k = 0; k < cnt; k++) {
        int kk = off + k; if (kk >= H_TOT) break;
        const float* p = emb_loc + (size_t)hloc[kk] * D_LOC + c * 8;
        float4 q0 = ((const float4*)p)[0];
        float4 q1 = ((const float4*)p)[1];
        a[0] += q0.x; a[1] += q0.y; a[2] += q0.z; a[3] += q0.w;
        a[4] += q1.x; a[5] += q1.y; a[6] += q1.z; a[7] += q1.w;
    }
    float inv = (cnt > 0) ? 1.0f / (float)cnt : 0.0f;
    u16* o = hist2 + (size_t)i * D_IN + c * 8;
    #pragma unroll
    for (int j = 0; j < 8; j++) o[j] = f2bf(a[j] * inv);
    // tim part: row at segment start
    hist2[(size_t)i * D_IN + D_LOC + c] = f2bf(emb_tim[(size_t)htim[off] * D_TIM + c]);
}

// ---------------- K2: x = [emb_loc[loc], emb_tim[tim]] (bf16 out) ----------------
__global__ __launch_bounds__(256) void build_x_kernel(const int* __restrict__ loc,
                                                      const int* __restrict__ tim,
                                                      const float* __restrict__ emb_loc,
                                                      const float* __restrict__ emb_tim,
                                                      u16* __restrict__ x) {
    int idx = blockIdx.x * 256 + threadIdx.x;    // < S_LEN * D_IN
    int row = idx / D_IN, col = idx - row * D_IN;
    float v = (col < D_LOC) ? emb_loc[(size_t)loc[row] * D_LOC + col]
                            : emb_tim[(size_t)tim[row] * D_TIM + (col - D_LOC)];
    x[idx] = f2bf(v);
}

// ---------------- K2b: uid columns of outbuf ----------------
__global__ __launch_bounds__(256) void uid_kernel(const int* __restrict__ uid,
                                                  const float* __restrict__ emb_uid,
                                                  u16* __restrict__ outbuf) {
    int idx = blockIdx.x * 256 + threadIdx.x;    // < TARGET * D_UID
    int row = idx >> 6, c = idx & 63;
    outbuf[(size_t)row * D_OUT + 2 * HID + c] = f2bf(emb_uid[(size_t)uid[0] * D_UID + c]);
}

// ---------------- GEMM: C(MxN) = A(MxK) @ B(NxK)^T [+bias][tanh][transposed copy] ----------------
// EPI bits: 1=bias, 2=tanh, 4=transposed bf16 store to Ct (ldt)
// AF32/BF32: source dtype of A/B (fp32 converts to bf16 at staging)
template<int EPI, bool OBF16, bool NG, bool AF32, bool BF32>
__global__ __launch_bounds__(256)
void gemm_bt_kernel(const void* __restrict__ Ap, const void* __restrict__ Bp,
                    void* __restrict__ Cp, const float* __restrict__ bias,
                    u16* __restrict__ Ct,
                    int M, int N, int K, int lda, int ldb, int ldc, int ldt) {
    __shared__ __align__(16) u16 sA[128 * 64];
    __shared__ __align__(16) u16 sB[128 * 64];
    const int tid = threadIdx.x;
    const int w = tid >> 6, lane = tid & 63;
    const int wr = (w >> 1) * 64, wc = (w & 1) * 64;
    const int m0 = blockIdx.y * 128, n0 = blockIdx.x * 128;
    f32x4 acc[4][4] = {};
    const int srow = w * 32 + (lane >> 3);   // + i*8
    const int scol = (lane & 7) * 8;         // element col within tile K=64

    for (int kt = 0; kt < K; kt += 64) {
        #pragma unroll
        for (int i = 0; i < 4; i++) {
            int rt = srow + i * 8;
            int ra = m0 + rt;
            if (AF32) {
                const float* s = (const float*)Ap + (size_t)ra * lda + kt + scol;
                float4 x0 = ((const float4*)s)[0];
                float4 x1 = ((const float4*)s)[1];
                uint4 q = { pk(x0.x, x0.y), pk(x0.z, x0.w), pk(x1.x, x1.y), pk(x1.z, x1.w) };
                *(uint4*)&sA[rt * 64 + scol] = q;
            } else {
                *(uint4*)&sA[rt * 64 + scol] =
                    *(const uint4*)((const u16*)Ap + (size_t)ra * lda + kt + scol);
            }
            int rb = n0 + rt;
            if (NG) rb = (rb < N - 1) ? rb : (N - 1);
            if (BF32) {
                const float* s = (const float*)Bp + (size_t)rb * ldb + kt + scol;
                float4 x0 = ((const float4*)s)[0];
                float4 x1 = ((const float4*)s)[1];
                uint4 q = { pk(x0.x, x0.y), pk(x0.z, x0.w), pk(x1.x, x1.y), pk(x1.z, x1.w) };
                *(uint4*)&sB[rt * 64 + scol] = q;
            } else {
                *(uint4*)&sB[rt * 64 + scol] =
                    *(const uint4*)((const u16*)Bp + (size_t)rb * ldb + kt + scol);
            }
        }
        __syncthreads();
        #pragma unroll
        for (int kk = 0; kk < 64; kk += 32) {
            const int krow = kk + (lane >> 4) * 8;
            bf16x8 af[4], bf_[4];
            #pragma unroll
            for (int mi = 0; mi < 4; mi++)
                af[mi] = *(const bf16x8*)&sA[(wr + mi * 16 + (lane & 15)) * 64 + krow];
            #pragma unroll
            for (int ni = 0; ni < 4; ni++)
                bf_[ni] = *(const bf16x8*)&sB[(wc + ni * 16 + (lane & 15)) * 64 + krow];
            #pragma unroll
            for (int mi = 0; mi < 4; mi++)
                #pragma unroll
                for (int ni = 0; ni < 4; ni++)
                    acc[mi][ni] = __builtin_amdgcn_mfma_f32_16x16x32_bf16(
                        af[mi], bf_[ni], acc[mi][ni], 0, 0, 0);
        }
        __syncthreads();
    }
    // epilogue: D col = lane&15, row = (lane>>4)*4 + reg
    #pragma unroll
    for (int mi = 0; mi < 4; mi++) {
        #pragma unroll
        for (int ni = 0; ni < 4; ni++) {
            int gc = n0 + wc + ni * 16 + (lane & 15);
            if (NG && gc >= N) continue;
            #pragma unroll
            for (int r = 0; r < 4; r++) {
                int gr = m0 + wr + mi * 16 + (lane >> 4) * 4 + r;
                float v = acc[mi][ni][r];
                if (EPI & 1) v += bias[gc];
                if (EPI & 2) v = tanh_stable(v);
                if (OBF16) ((u16*)Cp)[(size_t)gr * ldc + gc] = f2bf(v);
                else       ((float*)Cp)[(size_t)gr * ldc + gc] = v;
                if (EPI & 4) Ct[(size_t)gc * ldt + gr] = f2bf(v);
            }
        }
    }
}

// ---------------- GRU: 16 co-resident blocks, tag-packed h exchange ----------------
// block b owns h[32b..32b+32); holds w_hh rows {g*512 + 32b + jj} in VGPRs (fp32).
// thread layout: tid = qd*96 + wr, wr = g*32+jj, qd = quarter of K (128 each).
// Poll (round-4): 256 threads each poll ONE aligned 64-bit word-pair via
// __hip_atomic_load (agent scope, relaxed) -> exactly one serialized MALL round
// trip per poller per iteration (round 0 had two dependent trips for tid<128).
// Each dword carries its own tag and is checked independently, so no atomicity
// assumption beyond per-dword is needed. Same proven store protocol as round 0.
#define GRU_BLOCKS 16
__global__ __launch_bounds__(384, 2)
void gru_kernel(const float* __restrict__ gi, const float* __restrict__ w_hh,
                const float* __restrict__ b_hh, u32* __restrict__ hcomm,
                u16* __restrict__ outbuf) {
    const int b = blockIdx.x, tid = threadIdx.x;
    const int wr = tid % 96, qd = tid / 96;
    const int g = wr >> 5, jj = wr & 31;
    const int grow = g * HID + b * 32 + jj;     // row of w_hh / gi

    __shared__ __align__(16) float hbuf[HID];
    __shared__ float psum[96 * 4];
    __shared__ float ghh[96], gii[96];

    // preload weights: 128 fp32 in regs
    float wreg[128];
    {
        const float4* wp = (const float4*)(w_hh + (size_t)grow * HID + qd * 128);
        #pragma unroll
        for (int c = 0; c < 32; c++) {
            float4 v = wp[c];
            wreg[c * 4 + 0] = v.x; wreg[c * 4 + 1] = v.y;
            wreg[c * 4 + 2] = v.z; wreg[c * 4 + 3] = v.w;
        }
    }
    float bhh = b_hh[grow];
    for (int i = tid; i < HID; i += 384) hbuf[i] = 0.0f;
    float gi_cur = (qd == 0) ? gi[grow] : 0.0f;
    __syncthreads();

    for (int t = 0; t < S_LEN; t++) {
        // Phase 1: partial dot (reads full hbuf; LDS reads broadcast within wave)
        float acc = 0.0f;
        const float4* hp = (const float4*)(hbuf + qd * 128);
        #pragma unroll
        for (int c = 0; c < 32; c++) {
            float4 h4 = hp[c];
            acc = fmaf(wreg[4 * c + 0], h4.x, acc);
            acc = fmaf(wreg[4 * c + 1], h4.y, acc);
            acc = fmaf(wreg[4 * c + 2], h4.z, acc);
            acc = fmaf(wreg[4 * c + 3], h4.w, acc);
        }
        psum[wr * 4 + qd] = acc;
        __syncthreads();                                   // S1
        if (tid < 96) {
            float s = psum[tid * 4] + psum[tid * 4 + 1] + psum[tid * 4 + 2] + psum[tid * 4 + 3];
            ghh[tid] = s + bhh;
            gii[tid] = gi_cur;
        }
        __syncthreads();                                   // S2

        const u32 want = (u32)(t + 1);
        const int p = (t + 1) & 1;
        if (tid < 32) {
            float r = sigm(gii[tid] + ghh[tid]);
            float z = sigm(gii[32 + tid] + ghh[32 + tid]);
            float n = tanh_stable(gii[64 + tid] + r * ghh[64 + tid]);
            float hn = (1.0f - z) * n + z * hbuf[b * 32 + tid];
            u32 bits = (u32)f2bf(hn);
            __hip_atomic_store(&hcomm[p * HID + b * 32 + tid], (bits << 16) | want,
                               __ATOMIC_RELAXED, __HIP_MEMORY_SCOPE_AGENT);
            if (t >= (S_LEN - TARGET))
                outbuf[(size_t)(t - (S_LEN - TARGET)) * D_OUT + b * 32 + tid] = (u16)bits;
        }
        // prefetch next gi row element
        float gi_nxt = 0.0f;
        if (qd == 0) {
            int tn = (t + 1 < S_LEN) ? (t + 1) : (S_LEN - 1);
            gi_nxt = gi[(size_t)tn * G3 + grow];
        }
        // poll: 256 threads x one 64-bit load covers all 512 words
        if (t < S_LEN - 1 && tid < 256) {
            const u64* addr = (const u64*)&hcomm[p * HID + tid * 2];
            u32 v0, v1;
            for (;;) {
                u64 vv = __hip_atomic_load(addr, __ATOMIC_RELAXED, __HIP_MEMORY_SCOPE_AGENT);
                v0 = (u32)vv; v1 = (u32)(vv >> 32);
                if (((v0 & 0xffffu) == want) && ((v1 & 0xffffu) == want)) break;
            }
            hbuf[tid * 2 + 0] = u32_as_f32(v0 & 0xffff0000u);
            hbuf[tid * 2 + 1] = u32_as_f32(v1 & 0xffff0000u);
        }
        __syncthreads();                                   // S3
        gi_cur = gi_nxt;
    }
}

// ---------------- softmax over 1024 cols (scores fp32 -> attn bf16) ----------------
__global__ __launch_bounds__(256) void softmax_kernel(const float* __restrict__ sc,
                                                      u16* __restrict__ attn) {
    int r = blockIdx.x, tid = threadIdx.x;
    int lane = tid & 63, wv = tid >> 6;
    const float* row = sc + (size_t)r * NHIST;
    float v[4], m = -3.4e38f;
    #pragma unroll
    for (int k = 0; k < 4; k++) { v[k] = row[tid + 256 * k]; m = fmaxf(m, v[k]); }
    #pragma unroll
    for (int o = 32; o >= 1; o >>= 1) m = fmaxf(m, __shfl_xor(m, o));
    __shared__ float rmax[4], rsum[4];
    if (lane == 0) rmax[wv] = m;
    __syncthreads();
    m = fmaxf(fmaxf(rmax[0], rmax[1]), fmaxf(rmax[2], rmax[3]));
    float s = 0.0f;
    #pragma unroll
    for (int k = 0; k < 4; k++) { v[k] = __expf(v[k] - m); s += v[k]; }
    #pragma unroll
    for (int o = 32; o >= 1; o >>= 1) s += __shfl_xor(s, o);
    if (lane == 0) rsum[wv] = s;
    __syncthreads();
    s = rsum[0] + rsum[1] + rsum[2] + rsum[3];
    float inv = 1.0f / s;
    #pragma unroll
    for (int k = 0; k < 4; k++) attn[(size_t)r * NHIST + tid + 256 * k] = f2bf(v[k] * inv);
}

// ---------------- log_softmax in place over d_out rows (fp32) ----------------
__global__ __launch_bounds__(1024) void logsoftmax_kernel(float* __restrict__ y) {
    int r = blockIdx.x, tid = threadIdx.x;
    int lane = tid & 63, wv = tid >> 6;
    float* row = y + (size_t)r * NLOC;
    __shared__ float red[16];
    float m = -3.4e38f;
    for (int i = tid; i < NLOC; i += 1024) m = fmaxf(m, row[i]);
    #pragma unroll
    for (int o = 32; o >= 1; o >>= 1) m = fmaxf(m, __shfl_xor(m, o));
    if (lane == 0) red[wv] = m;
    __syncthreads();
    #pragma unroll
    for (int k = 0; k < 16; k++) m = fmaxf(m, red[k]);
    __syncthreads();
    float s = 0.0f;
    for (int i = tid; i < NLOC; i += 1024) s += __expf(row[i] - m);
    #pragma unroll
    for (int o = 32; o >= 1; o >>= 1) s += __shfl_xor(s, o);
    if (lane == 0) red[wv] = s;
    __syncthreads();
    float tot = 0.0f;
    #pragma unroll
    for (int k = 0; k < 16; k++) tot += red[k];
    float lse = m + logf(tot);
    for (int i = tid; i < NLOC; i += 1024) row[i] = row[i] - lse;
}

// ---------------- launch ----------------
extern "C" void kernel_launch(void* const* d_in, const int* in_sizes, int n_in,
                              void* d_out, int out_size, void* d_ws, size_t ws_size,
                              hipStream_t stream) {
    const int*   loc       = (const int*)d_in[0];
    const int*   tim       = (const int*)d_in[1];
    const int*   hloc      = (const int*)d_in[2];
    const int*   htim      = (const int*)d_in[3];
    const int*   counts    = (const int*)d_in[4];
    const int*   uid       = (const int*)d_in[5];
    // d_in[6] = target_len (1024, constant)
    const float* emb_loc   = (const float*)d_in[7];
    const float* emb_tim   = (const float*)d_in[8];
    const float* emb_uid   = (const float*)d_in[9];
    const float* fc_attn_w = (const float*)d_in[10];
    const float* fc_attn_b = (const float*)d_in[11];
    const float* w_ih      = (const float*)d_in[12];
    const float* w_hh      = (const float*)d_in[13];
    const float* b_ih      = (const float*)d_in[14];
    const float* b_hh      = (const float*)d_in[15];
    const float* fc_final_w= (const float*)d_in[16];
    const float* fc_final_b= (const float*)d_in[17];

    char* ws = (char*)d_ws;
    int*   offs     = (int*)(ws + 0);                  //   4 KB
    u32*   hcomm    = (u32*)(ws + 4096);               //   4 KB
    u16*   hist2    = (u16*)(ws + 8192);               // 1024*576*2
    u16*   xbuf     = (u16*)(ws + 1187840);            // 2048*576*2
    u16*   history  = (u16*)(ws + 3547136);            // 1024*512*2
    u16*   historyT = (u16*)(ws + 4595712);            // 512*1024*2
    u16*   outbuf   = (u16*)(ws + 5644288);            // 1024*1088*2
    float* scores   = (float*)(ws + 7872512);          // 1024*1024*4
    u16*   attn     = (u16*)(ws + 12066816);           // 1024*1024*2
    float* gi       = (float*)(ws + 14163968);         // 2048*1536*4 -> end 26746880

    float* out = (float*)d_out;

    // prep
    scan_kernel<<<1, 1024, 0, stream>>>(counts, offs);
    hist_kernel<<<NHIST, 64, 0, stream>>>(hloc, htim, counts, offs, emb_loc, emb_tim, hist2);
    build_x_kernel<<<(S_LEN * D_IN) / 256, 256, 0, stream>>>(loc, tim, emb_loc, emb_tim, xbuf);
    uid_kernel<<<(TARGET * D_UID) / 256, 256, 0, stream>>>(uid, emb_uid, outbuf);

    // history = tanh(hist2 @ fc_attn_w^T + b) (bf16), plus transposed copy
    gemm_bt_kernel<1 | 2 | 4, true, false, false, true><<<dim3(HID / 128, NHIST / 128), 256, 0, stream>>>(
        hist2, fc_attn_w, history, fc_attn_b, historyT,
        NHIST, HID, D_IN, D_IN, D_IN, HID, NHIST);

    // gi = x @ w_ih^T + b_ih (fp32 out)
    gemm_bt_kernel<1, false, false, false, true><<<dim3(G3 / 128, S_LEN / 128), 256, 0, stream>>>(
        xbuf, w_ih, gi, b_ih, nullptr,
        S_LEN, G3, D_IN, D_IN, D_IN, G3, 0);

    // sequential GRU (writes q -> outbuf cols [0,512))
    gru_kernel<<<GRU_BLOCKS, 384, 0, stream>>>(gi, w_hh, b_hh, hcomm, outbuf);

    // scores = q @ history^T (fp32)
    gemm_bt_kernel<0, false, false, false, false><<<dim3(NHIST / 128, TARGET / 128), 256, 0, stream>>>(
        outbuf, history, scores, nullptr, nullptr,
        TARGET, NHIST, HID, D_OUT, HID, NHIST, 0);

    // attn = softmax(scores)  (bf16)
    softmax_kernel<<<TARGET, 256, 0, stream>>>(scores, attn);

    // context = attn @ history -> outbuf cols [512,1024)
    gemm_bt_kernel<0, true, false, false, false><<<dim3(HID / 128, TARGET / 128), 256, 0, stream>>>(
        attn, historyT, outbuf + HID, nullptr, nullptr,
        TARGET, HID, NHIST, NHIST, NHIST, D_OUT, 0);

    // y = outbuf @ fc_final_w^T + b -> d_out (fp32), N ragged
    gemm_bt_kernel<1, false, true, false, true><<<dim3((NLOC + 127) / 128, TARGET / 128), 256, 0, stream>>>(
        outbuf, fc_final_w, out, fc_final_b, nullptr,
        TARGET, NLOC, D_OUT, D_OUT, D_OUT, NLOC, 0);

    // log_softmax in place
    logsoftmax_kernel<<<TARGET, 1024, 0, stream>>>(out);
}